// Round 3
// baseline (303.065 us; speedup 1.0000x reference)
//
#include <hip/hip_runtime.h>

#define NN 8192
#define INF_ 512
#define OUTF 256
#define LOG2E 1.4426950408889634f

typedef __attribute__((ext_vector_type(8))) short short8;
typedef __attribute__((ext_vector_type(4))) float f4;
typedef __attribute__((ext_vector_type(4))) int i4;

__device__ __forceinline__ unsigned short f2bf(float f) {
  union { float f; unsigned u; } v; v.f = f;
  unsigned r = v.u + 0x7fffu + ((v.u >> 16) & 1u);
  return (unsigned short)(r >> 16);
}
__device__ __forceinline__ float bf2f(unsigned short h) {
  union { unsigned u; float f; } v; v.u = ((unsigned)h) << 16;
  return v.f;
}

// ---------------- K0: W (512x256 f32) -> W^T hi/lo bf16 (256x512) ----------------
__global__ void k_wsplit(const float* __restrict__ W, unsigned short* __restrict__ Whi,
                         unsigned short* __restrict__ Wlo) {
  int idx = blockIdx.x * 256 + threadIdx.x;   // 131072
  int k = idx >> 8, c = idx & 255;
  float w = W[idx];
  unsigned short hi = f2bf(w);
  unsigned short lo = f2bf(w - bf2f(hi));
  Whi[c * INF_ + k] = hi;
  Wlo[c * INF_ + k] = lo;
}

// ---------------- K1: h = x@W (split-3 bf16 MFMA), h_T bf16, s1, s2 ----------------
// 512 blocks x 1 wave; block b: rows [b*16, +16), ALL 256 cols -> s1/s2 computed
// fully in-block (plain stores, no atomics, no memset). a pre-scaled by LOG2E.
__global__ void __launch_bounds__(64) k_h(
    const float* __restrict__ x, const float* __restrict__ a,
    const unsigned short* __restrict__ Whi, const unsigned short* __restrict__ Wlo,
    unsigned short* __restrict__ hT, float* __restrict__ s1, float* __restrict__ s2) {
  const int rowbase = blockIdx.x * 16;
  const int l = threadIdx.x;
  const int r15 = l & 15, kg = l >> 4;

  f4 acc[16];
#pragma unroll
  for (int i = 0; i < 16; ++i) acc[i] = (f4){0.f, 0.f, 0.f, 0.f};

  for (int kk = 0; kk < INF_; kk += 32) {
    const float* xp = x + (rowbase + r15) * INF_ + kk + kg * 8;
    f4 xa = *(const f4*)xp;
    f4 xb = *(const f4*)(xp + 4);
    short8 ahi, alo;
#pragma unroll
    for (int e = 0; e < 8; ++e) {
      float f = (e < 4) ? xa[e] : xb[e - 4];
      unsigned short h = f2bf(f);
      ahi[e] = (short)h;
      alo[e] = (short)f2bf(f - bf2f(h));
    }
#pragma unroll
    for (int cg = 0; cg < 16; ++cg) {
      int col = cg * 16 + r15;
      const short8 bhi = *(const short8*)(Whi + col * INF_ + kk + kg * 8);
      const short8 blo = *(const short8*)(Wlo + col * INF_ + kk + kg * 8);
      acc[cg] = __builtin_amdgcn_mfma_f32_16x16x32_bf16(ahi, bhi, acc[cg], 0, 0, 0);
      acc[cg] = __builtin_amdgcn_mfma_f32_16x16x32_bf16(ahi, blo, acc[cg], 0, 0, 0);
      acc[cg] = __builtin_amdgcn_mfma_f32_16x16x32_bf16(alo, bhi, acc[cg], 0, 0, 0);
    }
  }
  float sp1[4] = {0, 0, 0, 0}, sp2[4] = {0, 0, 0, 0};
#pragma unroll
  for (int cg = 0; cg < 16; ++cg) {
    int col = cg * 16 + r15;
    float a1v = a[col] * LOG2E, a2v = a[OUTF + col] * LOG2E;
#pragma unroll
    for (int r = 0; r < 4; ++r) {
      float v = acc[cg][r];
      hT[col * NN + rowbase + kg * 4 + r] = f2bf(v);
      sp1[r] += v * a1v;
      sp2[r] += v * a2v;
    }
  }
#pragma unroll
  for (int r = 0; r < 4; ++r) {
#pragma unroll
    for (int m = 1; m < 16; m <<= 1) {
      sp1[r] += __shfl_xor(sp1[r], m, 16);
      sp2[r] += __shfl_xor(sp2[r], m, 16);
    }
    if (r15 == 0) {
      s1[rowbase + kg * 4 + r] = sp1[r];
      s2[rowbase + kg * 4 + r] = sp2[r];
    }
  }
}

// ---------------- K2: producer/consumer fused attention ----------------
// 256 blocks x 8 waves. Block owns rows [b*32,+32) x ALL j (128 tiles of 64 j).
// Waves 0-3 (producers): stream adj+s2 (HBM, own vmcnt queue, depth-2 reg
//   prefetch), compute w = bf16(exp2(leakyrelu(s1'+s2'))), ds_write swizzled
//   w-tile, track lsum of ROUNDED w. Waves 4-7 (consumers): per wave 64 cols;
//   A-frags from LDS (lgkmcnt), B-frags from L2-resident hT (pure-L2 vmcnt
//   queue), 16 MFMA/iter. One raw s_barrier per phase; only manual wait is
//   lgkmcnt(0) before producer barriers. No atomics; out written directly.
__global__ void __launch_bounds__(512, 1) k_attn(
    const int* __restrict__ adj, const float* __restrict__ s1G,
    const float* __restrict__ s2G, const unsigned short* __restrict__ hT,
    const float* __restrict__ biasG, float* __restrict__ out) {
  __shared__ unsigned short wlds[2][2048];   // [32 rows][64 j] bf16, slot-swizzled
  __shared__ float lsumLDS[32];
  const int rowbase = blockIdx.x * 32;
  const int tid = threadIdx.x;
  const int wv = tid >> 6;
  const int l = tid & 63;

  if (wv < 4) {
    // ---------------- producer ----------------
    const int r_loc = wv * 8 + (l >> 3);     // local row 0..31
    const int jseg = l & 7;                  // which 8-j segment of the 64-j tile
    const int row = rowbase + r_loc;
    const float s1v = s1G[row];              // pre-scaled by LOG2E
    const int swz = jseg ^ (r_loc & 7);      // LDS bank swizzle slot
    float lsum = 0.f;

    const int* aprow = adj + row * NN + jseg * 8;
    const float* sprow = s2G + jseg * 8;

    // depth-2 register prefetch: cur = tile p, nx = tile p+1; issue p+2 each iter
    i4 cA0 = *(const i4*)(aprow);
    i4 cA1 = *(const i4*)(aprow + 4);
    f4 cS0 = *(const f4*)(sprow);
    f4 cS1 = *(const f4*)(sprow + 4);
    i4 nA0 = *(const i4*)(aprow + 64);
    i4 nA1 = *(const i4*)(aprow + 68);
    f4 nS0 = *(const f4*)(sprow + 64);
    f4 nS1 = *(const f4*)(sprow + 68);

    for (int p = 0; p < 128; ++p) {
      const int jf = (p + 2 < 128 ? p + 2 : 127) * 64;   // clamped, unconditional
      i4 fA0 = *(const i4*)(aprow + jf);
      i4 fA1 = *(const i4*)(aprow + jf + 4);
      f4 fS0 = *(const f4*)(sprow + jf);
      f4 fS1 = *(const f4*)(sprow + jf + 4);

      short8 wpack;
#pragma unroll
      for (int e = 0; e < 8; ++e) {
        float sv = (e < 4) ? cS0[e] : cS1[e - 4];
        int m = (e < 4) ? cA0[e] : cA1[e - 4];
        float xx = s1v + sv;
        float lr = fmaxf(xx, 0.2f * xx);
        float pp = __builtin_amdgcn_exp2f(lr);
        float w0 = (m > 0) ? pp : 0.0f;
        unsigned short hh = f2bf(w0);
        wpack[e] = (short)hh;
        lsum += bf2f(hh);   // sum ROUNDED weights -> exact convex combination
      }
      *(short8*)&wlds[p & 1][r_loc * 64 + swz * 8] = wpack;
      asm volatile("s_waitcnt lgkmcnt(0)" ::: "memory");
      __builtin_amdgcn_s_barrier();

      cA0 = nA0; cA1 = nA1; cS0 = nS0; cS1 = nS1;
      nA0 = fA0; nA1 = fA1; nS0 = fS0; nS1 = fS1;
    }
    // final phase: reduce lsum over jseg lanes, publish to LDS
    lsum += __shfl_xor(lsum, 1, 64);
    lsum += __shfl_xor(lsum, 2, 64);
    lsum += __shfl_xor(lsum, 4, 64);
    if (jseg == 0) lsumLDS[r_loc] = lsum;
    asm volatile("s_waitcnt lgkmcnt(0)" ::: "memory");
    __builtin_amdgcn_s_barrier();
  } else {
    // ---------------- consumer ----------------
    const int cw = wv - 4;
    const int r15 = l & 15, kg = l >> 4;
    const int colbase = cw * 64;
    f4 acc0[4], acc1[4];
#pragma unroll
    for (int c = 0; c < 4; ++c) {
      acc0[c] = (f4){0.f, 0.f, 0.f, 0.f};
      acc1[c] = (f4){0.f, 0.f, 0.f, 0.f};
    }
    __builtin_amdgcn_s_barrier();   // wait for tile 0
    for (int q = 0; q < 128; ++q) {
      const int jt = q * 64;
      // B-frags from hT (L2): consumer's vmcnt queue is pure L2 loads
      short8 bf[2][4];
#pragma unroll
      for (int ks = 0; ks < 2; ++ks)
#pragma unroll
        for (int cg = 0; cg < 4; ++cg)
          bf[ks][cg] = *(const short8*)(hT + (colbase + cg * 16 + r15) * NN + jt + ks * 32 + kg * 8);
      // A-frags from LDS (lgkmcnt, independent counter)
      short8 af[2][2];
#pragma unroll
      for (int ks = 0; ks < 2; ++ks)
#pragma unroll
        for (int g = 0; g < 2; ++g) {
          const int rA = g * 16 + r15;
          af[ks][g] = *(const short8*)&wlds[q & 1][rA * 64 + (((ks * 4 + kg) ^ (rA & 7)) << 3)];
        }
#pragma unroll
      for (int ks = 0; ks < 2; ++ks)
#pragma unroll
        for (int cg = 0; cg < 4; ++cg) {
          acc0[cg] = __builtin_amdgcn_mfma_f32_16x16x32_bf16(af[ks][0], bf[ks][cg], acc0[cg], 0, 0, 0);
          acc1[cg] = __builtin_amdgcn_mfma_f32_16x16x32_bf16(af[ks][1], bf[ks][cg], acc1[cg], 0, 0, 0);
        }
      __builtin_amdgcn_s_barrier();
    }
    // epilogue: normalize + bias, direct store (no atomics)
    float inv0[4], inv1[4];
#pragma unroll
    for (int r = 0; r < 4; ++r) {
      inv0[r] = 1.0f / lsumLDS[kg * 4 + r];
      inv1[r] = 1.0f / lsumLDS[16 + kg * 4 + r];
    }
#pragma unroll
    for (int cg = 0; cg < 4; ++cg) {
      const int col = colbase + cg * 16 + r15;
      const float bv = biasG[col];
#pragma unroll
      for (int r = 0; r < 4; ++r) {
        out[(rowbase + kg * 4 + r) * OUTF + col] = acc0[cg][r] * inv0[r] + bv;
        out[(rowbase + 16 + kg * 4 + r) * OUTF + col] = acc1[cg][r] * inv1[r] + bv;
      }
    }
  }
}

extern "C" void kernel_launch(void* const* d_in, const int* in_sizes, int n_in,
                              void* d_out, int out_size, void* d_ws, size_t ws_size,
                              hipStream_t stream) {
  const float* x = (const float*)d_in[0];
  const int* adj = (const int*)d_in[1];
  const float* W = (const float*)d_in[2];
  const float* a = (const float*)d_in[3];
  const float* bias = (const float*)d_in[4];
  float* out = (float*)d_out;

  char* ws = (char*)d_ws;
  unsigned short* hT  = (unsigned short*)(ws);               // 4 MB  [256][8192] bf16
  unsigned short* Whi = (unsigned short*)(ws + 4194304);     // 256 KB [256][512]
  unsigned short* Wlo = (unsigned short*)(ws + 4456448);     // 256 KB
  float* s1 = (float*)(ws + 4718592);                        // 32 KB
  float* s2 = (float*)(ws + 4751360);                        // 32 KB

  k_wsplit<<<512, 256, 0, stream>>>(W, Whi, Wlo);
  k_h<<<512, 64, 0, stream>>>(x, a, Whi, Wlo, hT, s1, s2);
  k_attn<<<256, 512, 0, stream>>>(adj, s1, s2, hT, bias, out);
}

// Round 4
// 204.274 us; speedup vs baseline: 1.4836x; 1.4836x over previous
//
#include <hip/hip_runtime.h>

#define NN 8192
#define INF_ 512
#define OUTF 256
#define LOG2E 1.4426950408889634f

typedef __attribute__((ext_vector_type(8))) short short8;
typedef __attribute__((ext_vector_type(4))) float f4;
typedef __attribute__((ext_vector_type(4))) int i4;

__device__ __forceinline__ unsigned short f2bf(float f) {
  union { float f; unsigned u; } v; v.f = f;
  unsigned r = v.u + 0x7fffu + ((v.u >> 16) & 1u);
  return (unsigned short)(r >> 16);
}
__device__ __forceinline__ float bf2f(unsigned short h) {
  union { unsigned u; float f; } v; v.u = ((unsigned)h) << 16;
  return v.f;
}

// ---------------- K0: W (512x256 f32) -> W^T hi/lo bf16 (256x512) ----------------
__global__ void k_wsplit(const float* __restrict__ W, unsigned short* __restrict__ Whi,
                         unsigned short* __restrict__ Wlo) {
  int idx = blockIdx.x * 256 + threadIdx.x;   // 131072
  int k = idx >> 8, c = idx & 255;
  float w = W[idx];
  unsigned short hi = f2bf(w);
  unsigned short lo = f2bf(w - bf2f(hi));
  Whi[c * INF_ + k] = hi;
  Wlo[c * INF_ + k] = lo;
}

// ---------------- K1: h = x@W (split-3 bf16 MFMA), h_T bf16, s1, s2 ----------------
// 512 blocks x 1 wave; block b: rows [b*16,+16), ALL 256 cols. a pre-scaled by LOG2E.
__global__ void __launch_bounds__(64) k_h(
    const float* __restrict__ x, const float* __restrict__ a,
    const unsigned short* __restrict__ Whi, const unsigned short* __restrict__ Wlo,
    unsigned short* __restrict__ hT, float* __restrict__ s1, float* __restrict__ s2) {
  const int rowbase = blockIdx.x * 16;
  const int l = threadIdx.x;
  const int r15 = l & 15, kg = l >> 4;

  f4 acc[16];
#pragma unroll
  for (int i = 0; i < 16; ++i) acc[i] = (f4){0.f, 0.f, 0.f, 0.f};

  for (int kk = 0; kk < INF_; kk += 32) {
    const float* xp = x + (rowbase + r15) * INF_ + kk + kg * 8;
    f4 xa = *(const f4*)xp;
    f4 xb = *(const f4*)(xp + 4);
    short8 ahi, alo;
#pragma unroll
    for (int e = 0; e < 8; ++e) {
      float f = (e < 4) ? xa[e] : xb[e - 4];
      unsigned short h = f2bf(f);
      ahi[e] = (short)h;
      alo[e] = (short)f2bf(f - bf2f(h));
    }
#pragma unroll
    for (int cg = 0; cg < 16; ++cg) {
      int col = cg * 16 + r15;
      const short8 bhi = *(const short8*)(Whi + col * INF_ + kk + kg * 8);
      const short8 blo = *(const short8*)(Wlo + col * INF_ + kk + kg * 8);
      acc[cg] = __builtin_amdgcn_mfma_f32_16x16x32_bf16(ahi, bhi, acc[cg], 0, 0, 0);
      acc[cg] = __builtin_amdgcn_mfma_f32_16x16x32_bf16(ahi, blo, acc[cg], 0, 0, 0);
      acc[cg] = __builtin_amdgcn_mfma_f32_16x16x32_bf16(alo, bhi, acc[cg], 0, 0, 0);
    }
  }
  float sp1[4] = {0, 0, 0, 0}, sp2[4] = {0, 0, 0, 0};
#pragma unroll
  for (int cg = 0; cg < 16; ++cg) {
    int col = cg * 16 + r15;
    float a1v = a[col] * LOG2E, a2v = a[OUTF + col] * LOG2E;
#pragma unroll
    for (int r = 0; r < 4; ++r) {
      float v = acc[cg][r];
      hT[col * NN + rowbase + kg * 4 + r] = f2bf(v);
      sp1[r] += v * a1v;
      sp2[r] += v * a2v;
    }
  }
#pragma unroll
  for (int r = 0; r < 4; ++r) {
#pragma unroll
    for (int m = 1; m < 16; m <<= 1) {
      sp1[r] += __shfl_xor(sp1[r], m, 16);
      sp2[r] += __shfl_xor(sp2[r], m, 16);
    }
    if (r15 == 0) {
      s1[rowbase + kg * 4 + r] = sp1[r];
      s2[rowbase + kg * 4 + r] = sp2[r];
    }
  }
}

// ---------------- K2: fused mask + exp + (attention-partial @ h) ----------------
// 512 blocks (2/CU) x 4 waves. Block: 64 rows x 2048-j chunk (chunk=b&3, XCD-aligned),
// 32 phases of 64 j. adj staged by global_load_lds, depth-3 slots, per-wave counted
// vmcnt (each wave reads ONLY rows its own glls wrote -> no barrier for adj).
// w handoff via one 8KB XOR-swizzled LDS buffer, 2 raw s_barriers per phase.
// B-frags issued BEFORE glls so their auto-wait is vmcnt(4): glls span phases.
__global__ void __launch_bounds__(256, 2) k_attn(
    const int* __restrict__ adj, const float* __restrict__ s1G,
    const float* __restrict__ s2G, const unsigned short* __restrict__ hT,
    float* __restrict__ accG, float* __restrict__ lG) {
  __shared__ int adjb[3][4096];          // 3 x 16KB: [64 rows][16 granules of 4 ints], XOR-16 swz
  __shared__ unsigned short wbuf[4096];  // 8KB: [64 rows][8 granules of 8 bf16], XOR-8 swz
  __shared__ float s2l[2048];            // 8KB: this chunk's s2 (pre-scaled by LOG2E)

  const int b = blockIdx.x;
  const int chunk = b & 3;
  const int rowbase = (b >> 2) * 64;
  const int jchunk = chunk * 2048;
  const int tid = threadIdx.x;
  const int wv = tid >> 6;
  const int l = tid & 63;
  const int r15 = l & 15, kg = l >> 4;
  const int row_w = wv * 16 + r15;       // w-compute row (own wave's staged rows)
  const int colbase = wv * 64;           // consumer cols

  const float s1v = s1G[rowbase + row_w];   // pre-scaled by LOG2E

  // ---- prologue: stage s2 chunk to LDS, then gll adj tiles 0,1 ----
  {
    const float* sp = s2G + jchunk + tid * 8;
    f4 v0 = *(const f4*)sp;
    f4 v1 = *(const f4*)(sp + 4);
    *(f4*)&s2l[tid * 8] = v0;
    *(f4*)&s2l[tid * 8 + 4] = v1;
  }
#pragma unroll
  for (int p = 0; p < 2; ++p) {
    const int jn = jchunk + p * 64;
#pragma unroll
    for (int q = 0; q < 4; ++q) {
      const int row_t = (wv * 4 + q) * 4 + kg;
      const int s = r15 ^ (row_t & 15);
      const int* src = adj + (rowbase + row_t) * NN + jn + s * 4;
      __builtin_amdgcn_global_load_lds(
          (const __attribute__((address_space(1))) unsigned int*)src,
          (__attribute__((address_space(3))) unsigned int*)&adjb[p][(wv * 4 + q) * 256], 16, 0, 0);
    }
  }
  asm volatile("s_waitcnt lgkmcnt(0)" ::: "memory");
  __builtin_amdgcn_s_barrier();   // s2l visible

  f4 acc[4][4];
#pragma unroll
  for (int rg = 0; rg < 4; ++rg)
#pragma unroll
    for (int cg = 0; cg < 4; ++cg) acc[rg][cg] = (f4){0.f, 0.f, 0.f, 0.f};
  float lsum = 0.f;

  for (int t = 0; t < 32; ++t) {
    const int jt = jchunk + t * 64;
    // ---- issue B(t) FIRST (8 dwordx4; auto-wait later = vmcnt(4), keeps glls in flight)
    short8 bfr[2][4];
#pragma unroll
    for (int ks = 0; ks < 2; ++ks)
#pragma unroll
      for (int cg = 0; cg < 4; ++cg)
        bfr[ks][cg] = *(const short8*)(hT + (colbase + cg * 16 + r15) * NN + jt + ks * 32 + kg * 8);
    // ---- issue gll adj(t+2) (slot (t+2)%3; tail clamps to tile 31, never read)
    {
      const int tn = (t + 2 <= 31) ? t + 2 : 31;
      const int slot = (t + 2) % 3;
      const int jn = jchunk + tn * 64;
#pragma unroll
      for (int q = 0; q < 4; ++q) {
        const int row_t = (wv * 4 + q) * 4 + kg;
        const int s = r15 ^ (row_t & 15);
        const int* src = adj + (rowbase + row_t) * NN + jn + s * 4;
        __builtin_amdgcn_global_load_lds(
            (const __attribute__((address_space(1))) unsigned int*)src,
            (__attribute__((address_space(3))) unsigned int*)&adjb[slot][(wv * 4 + q) * 256], 16, 0, 0);
      }
    }
    // ---- counted wait: guarantees adj(t)'s glls (issued 2 phases ago) completed.
    // per-phase vm ops = 12 (8 B + 4 gll); issued-after-adj(t) = 24 steady, 16 at t=0.
    if (t == 0) asm volatile("s_waitcnt vmcnt(12)" ::: "memory");
    else        asm volatile("s_waitcnt vmcnt(24)" ::: "memory");
    // ---- read own-wave adj rows from LDS, compute w, pack, ds_write swizzled ----
    const int slotc = t % 3;
    i4 av[4];
#pragma unroll
    for (int k = 0; k < 4; ++k)
      av[k] = *(const i4*)&adjb[slotc][row_w * 64 + (((kg * 4 + k) ^ (row_w & 15)) << 2)];
    f4 s2v[4];
#pragma unroll
    for (int k = 0; k < 4; ++k)
      s2v[k] = *(const f4*)&s2l[t * 64 + kg * 16 + k * 4];
    unsigned short wp[16];
#pragma unroll
    for (int k = 0; k < 4; ++k)
#pragma unroll
      for (int e2 = 0; e2 < 4; ++e2) {
        float xx = s1v + s2v[k][e2];
        float lr = fmaxf(xx, 0.2f * xx);
        float pp = __builtin_amdgcn_exp2f(lr);
        float w0 = (av[k][e2] > 0) ? pp : 0.0f;
        unsigned short hh = f2bf(w0);
        wp[k * 4 + e2] = hh;
        lsum += bf2f(hh);   // sum ROUNDED weights -> exact convex combination
      }
    short8 w0p, w1p;
#pragma unroll
    for (int e = 0; e < 8; ++e) { w0p[e] = (short)wp[e]; w1p[e] = (short)wp[8 + e]; }
    *(short8*)&wbuf[row_w * 64 + (((kg * 2) ^ (row_w & 7)) << 3)] = w0p;
    *(short8*)&wbuf[row_w * 64 + (((kg * 2 + 1) ^ (row_w & 7)) << 3)] = w1p;
    asm volatile("s_waitcnt lgkmcnt(0)" ::: "memory");
    __builtin_amdgcn_s_barrier();   // w(t) visible to all waves
    // ---- A-frags (swizzled) + 32 MFMAs ----
    short8 afr[2][4];
#pragma unroll
    for (int ks = 0; ks < 2; ++ks)
#pragma unroll
      for (int rg = 0; rg < 4; ++rg) {
        const int rr = rg * 16 + r15;
        afr[ks][rg] = *(const short8*)&wbuf[rr * 64 + (((ks * 4 + kg) ^ (rr & 7)) << 3)];
      }
#pragma unroll
    for (int ks = 0; ks < 2; ++ks)
#pragma unroll
      for (int rg = 0; rg < 4; ++rg)
#pragma unroll
        for (int cg = 0; cg < 4; ++cg)
          acc[rg][cg] = __builtin_amdgcn_mfma_f32_16x16x32_bf16(afr[ks][rg], bfr[ks][cg], acc[rg][cg], 0, 0, 0);
    __builtin_amdgcn_s_barrier();   // wbuf consumed; next phase may overwrite
  }

  // ---- epilogue: row-sum partials + acc partials via atomics ----
  lsum += __shfl_xor(lsum, 16, 64);
  lsum += __shfl_xor(lsum, 32, 64);
  if (kg == 0) atomicAdd(&lG[rowbase + row_w], lsum);
#pragma unroll
  for (int rg = 0; rg < 4; ++rg)
#pragma unroll
    for (int cg = 0; cg < 4; ++cg)
#pragma unroll
      for (int r = 0; r < 4; ++r)
        atomicAdd(&accG[(rowbase + rg * 16 + kg * 4 + r) * OUTF + colbase + cg * 16 + r15],
                  acc[rg][cg][r]);
}

// ---------------- K3: out = acc / l + bias ----------------
__global__ void k_final(const float* __restrict__ accG, const float* __restrict__ lG,
                        const float* __restrict__ bias, float* __restrict__ out) {
  int idx = blockIdx.x * 256 + threadIdx.x;  // f4 index, 524288 total
  int row = idx >> 6;
  int c4 = idx & 63;
  f4 v = ((const f4*)accG)[idx];
  float inv = 1.0f / lG[row];
  f4 bb = ((const f4*)bias)[c4];
  f4 o;
#pragma unroll
  for (int e = 0; e < 4; ++e) o[e] = v[e] * inv + bb[e];
  ((f4*)out)[idx] = o;
}

extern "C" void kernel_launch(void* const* d_in, const int* in_sizes, int n_in,
                              void* d_out, int out_size, void* d_ws, size_t ws_size,
                              hipStream_t stream) {
  const float* x = (const float*)d_in[0];
  const int* adj = (const int*)d_in[1];
  const float* W = (const float*)d_in[2];
  const float* a = (const float*)d_in[3];
  const float* bias = (const float*)d_in[4];
  float* out = (float*)d_out;

  char* ws = (char*)d_ws;
  float* accG = (float*)(ws);                                // 8 MB
  float* lG   = (float*)(ws + 8388608);                      // 32 KB
  unsigned short* hT  = (unsigned short*)(ws + 8421376);     // 4 MB  [256][8192] bf16
  unsigned short* Whi = (unsigned short*)(ws + 12615680);    // 256 KB [256][512]
  unsigned short* Wlo = (unsigned short*)(ws + 12877824);    // 256 KB
  float* s1 = (float*)(ws + 13139968);                       // 32 KB
  float* s2 = (float*)(ws + 13172736);                       // 32 KB

  hipMemsetAsync(accG, 0, 8421376, stream);  // zero acc + l
  k_wsplit<<<512, 256, 0, stream>>>(W, Whi, Wlo);
  k_h<<<512, 64, 0, stream>>>(x, a, Whi, Wlo, hT, s1, s2);
  k_attn<<<512, 256, 0, stream>>>(adj, s1, s2, hT, accG, lG);
  k_final<<<2048, 256, 0, stream>>>(accG, lG, bias, out);
}